// Round 1
// baseline (4638.118 us; speedup 1.0000x reference)
//
#include <hip/hip_runtime.h>
#include <math.h>

#define BATCH 2048
#define SEQ   128
#define HID   512
#define OUTT  24

#define BM 64
#define BN 64
#define BK 32

// One RNN step: h_out = tanh(inp ⊗ Wih + bih + bhh + h_in @ Whh^T)
// inp[b] = inp_vec[b*inp_stride + inp_off]  (encoder: x, stride=SEQ, off=t;
//                                            decoder: dec_in, stride=1, off=0)
__global__ __launch_bounds__(256) void rnn_step(
    const float* __restrict__ h_in,
    float*       __restrict__ h_out,
    const float* __restrict__ Whh,   // HID x HID row-major; C[b,j] = sum_k h[b,k]*Whh[j*HID+k]
    const float* __restrict__ Wih,   // HID (I==1)
    const float* __restrict__ bih,
    const float* __restrict__ bhh,
    const float* __restrict__ inp_vec,
    int inp_stride, int inp_off)
{
    __shared__ float As[BK][BM + 4];  // k-major: As[k][row]
    __shared__ float Bs[BK][BN + 4];

    const int tid   = threadIdx.x;
    const int jBase = blockIdx.x * BN;   // hidden-out tile
    const int bBase = blockIdx.y * BM;   // batch tile

    const int tx4 = (tid & 15) * 4;   // 16 cols of threads -> 64 j's
    const int ty4 = (tid >> 4) * 4;   // 16 rows of threads -> 64 b's

    float acc[4][4] = {};

    for (int k0 = 0; k0 < HID; k0 += BK) {
        // stage A (h tile) and B (Whh tile), 2048 elems each, 8 per thread
        #pragma unroll
        for (int i = 0; i < 8; i++) {
            int li = tid + i * 256;
            int r  = li >> 5;    // 0..63
            int c  = li & 31;    // 0..31
            As[c][r] = h_in[(size_t)(bBase + r) * HID + k0 + c];
            Bs[c][r] = Whh [(size_t)(jBase + r) * HID + k0 + c];
        }
        __syncthreads();

        #pragma unroll
        for (int kk = 0; kk < BK; kk++) {
            float4 av = *reinterpret_cast<const float4*>(&As[kk][ty4]);
            float4 bv = *reinterpret_cast<const float4*>(&Bs[kk][tx4]);
            float ar[4] = {av.x, av.y, av.z, av.w};
            float bc[4] = {bv.x, bv.y, bv.z, bv.w};
            #pragma unroll
            for (int r = 0; r < 4; r++)
                #pragma unroll
                for (int c = 0; c < 4; c++)
                    acc[r][c] += ar[r] * bc[c];
        }
        __syncthreads();
    }

    // epilogue: + inp*Wih[j] + bih[j] + bhh[j], tanh, store
    float wj[4], bj[4];
    #pragma unroll
    for (int c = 0; c < 4; c++) {
        int j = jBase + tx4 + c;
        wj[c] = Wih[j];
        bj[c] = bih[j] + bhh[j];
    }
    #pragma unroll
    for (int r = 0; r < 4; r++) {
        int b = bBase + ty4 + r;
        float inp = inp_vec[(size_t)b * inp_stride + inp_off];
        #pragma unroll
        for (int c = 0; c < 4; c++) {
            int j = jBase + tx4 + c;
            float v = acc[r][c] + inp * wj[c] + bj[c];
            h_out[(size_t)b * HID + j] = tanhf(v);
        }
    }
}

// out[b] = dot(h[b,:], fcW) + fcb ; also feeds dec_in for next step.
// One wave (64 lanes) per batch row.
__global__ __launch_bounds__(256) void fc_step(
    const float* __restrict__ h,
    const float* __restrict__ fcW,
    const float* __restrict__ fcb,
    float* __restrict__ dec_in,
    float* __restrict__ out, int t)
{
    int gtid = blockIdx.x * blockDim.x + threadIdx.x;
    int row  = gtid >> 6;
    int lane = threadIdx.x & 63;
    if (row >= BATCH) return;
    const float* hr = h + (size_t)row * HID;
    float s = 0.f;
    #pragma unroll
    for (int k = 0; k < HID / 64; k++)
        s += hr[lane + k * 64] * fcW[lane + k * 64];
    #pragma unroll
    for (int off = 32; off > 0; off >>= 1)
        s += __shfl_down(s, off, 64);
    if (lane == 0) {
        float o = s + fcb[0];
        dec_in[row]           = o;
        out[(size_t)row * OUTT + t] = o;
    }
}

__global__ void init_decin(const float* __restrict__ x, float* __restrict__ dec_in)
{
    int b = blockIdx.x * blockDim.x + threadIdx.x;
    if (b < BATCH) dec_in[b] = x[(size_t)b * SEQ + (SEQ - 1)];
}

extern "C" void kernel_launch(void* const* d_in, const int* in_sizes, int n_in,
                              void* d_out, int out_size, void* d_ws, size_t ws_size,
                              hipStream_t stream)
{
    const float* x        = (const float*)d_in[0];
    const float* enc_Wih  = (const float*)d_in[1];
    const float* enc_Whh  = (const float*)d_in[2];
    const float* enc_bih  = (const float*)d_in[3];
    const float* enc_bhh  = (const float*)d_in[4];
    const float* dec_Wih  = (const float*)d_in[5];
    const float* dec_Whh  = (const float*)d_in[6];
    const float* dec_bih  = (const float*)d_in[7];
    const float* dec_bhh  = (const float*)d_in[8];
    const float* fc_W     = (const float*)d_in[9];
    const float* fc_b     = (const float*)d_in[10];
    float* out = (float*)d_out;

    char* ws = (char*)d_ws;
    const size_t hbytes = (size_t)BATCH * HID * sizeof(float);  // 4 MB
    float* hA     = (float*)(ws);
    float* hB     = (float*)(ws + hbytes);
    float* dec_in = (float*)(ws + 2 * hbytes);

    hipMemsetAsync(hA, 0, hbytes, stream);  // h0 = 0 (ws is poisoned each call)

    dim3 grid(HID / BN, BATCH / BM);  // (8, 32)
    dim3 block(256);

    float* cur = hA;
    float* nxt = hB;

    // encoder: 128 steps
    for (int t = 0; t < SEQ; t++) {
        rnn_step<<<grid, block, 0, stream>>>(cur, nxt, enc_Whh, enc_Wih,
                                             enc_bih, enc_bhh, x, SEQ, t);
        float* tmp = cur; cur = nxt; nxt = tmp;
    }

    // decoder init: dec_in = x[:, -1, 0]
    init_decin<<<BATCH / 256, 256, 0, stream>>>(x, dec_in);

    // decoder: 24 steps, autoregressive through dec_in
    for (int t = 0; t < OUTT; t++) {
        rnn_step<<<grid, block, 0, stream>>>(cur, nxt, dec_Whh, dec_Wih,
                                             dec_bih, dec_bhh, dec_in, 1, 0);
        fc_step<<<(BATCH * 64) / 256, 256, 0, stream>>>(nxt, fc_W, fc_b,
                                                        dec_in, out, t);
        float* tmp = cur; cur = nxt; nxt = tmp;
    }
}

// Round 2
// 3773.891 us; speedup vs baseline: 1.2290x; 1.2290x over previous
//
#include <hip/hip_runtime.h>
#include <math.h>

#define BATCH 2048
#define SEQ   128
#define HID   512
#define OUTT  24
#define RPB   8            // batch rows per block
#define NBLK  (BATCH/RPB)  // 256 blocks = 1 per CU

// W[j][k] (row-major HIDxHID) -> Wt[k][j] so that lane t reads Wt[k][2t] coalesced.
__global__ __launch_bounds__(256) void transpose_w(const float* __restrict__ W,
                                                   float* __restrict__ Wt)
{
    __shared__ float tile[32][33];
    int jb = blockIdx.x * 32, kb = blockIdx.y * 32;
    int tx = threadIdx.x & 31, ty = threadIdx.x >> 5;   // 32 x 8
    #pragma unroll
    for (int i = 0; i < 32; i += 8)
        tile[ty + i][tx] = W[(size_t)(jb + ty + i) * HID + kb + tx];
    __syncthreads();
    #pragma unroll
    for (int i = 0; i < 32; i += 8)
        Wt[(size_t)(kb + i + ty) * HID + jb + tx] = tile[tx][i + ty];
}

// Persistent kernel: block owns RPB batch rows for the entire 152-step sequence.
// h ping-pongs in LDS; Whh streams from L2 (k-major); decoder FC fused in-block.
__global__ __launch_bounds__(256, 1) void rnn_persist(
    const float* __restrict__ x,        // [BATCH][SEQ]
    const float* __restrict__ WtEnc,    // [HID][HID] k-major
    const float* __restrict__ WtDec,    // [HID][HID] k-major
    const float* __restrict__ encWih,   // [HID]
    const float* __restrict__ encBih,
    const float* __restrict__ encBhh,
    const float* __restrict__ decWih,
    const float* __restrict__ decBih,
    const float* __restrict__ decBhh,
    const float* __restrict__ fcW,      // [HID]
    const float* __restrict__ fcB,      // [1]
    float* __restrict__ out)            // [BATCH][OUTT]
{
    __shared__ float hbuf[2][RPB][HID];   // 32 KB ping-pong
    __shared__ float dec_in_s[RPB];

    const int tid  = threadIdx.x;
    const int row0 = blockIdx.x * RPB;
    const int j0   = tid * 2;            // each thread owns 2 hidden outputs

    // hoist per-thread scalar weights (enc & dec)
    const float eWi0 = encWih[j0],    eWi1 = encWih[j0 + 1];
    const float eB0  = encBih[j0] + encBhh[j0];
    const float eB1  = encBih[j0 + 1] + encBhh[j0 + 1];
    const float dWi0 = decWih[j0],    dWi1 = decWih[j0 + 1];
    const float dB0  = decBih[j0] + decBhh[j0];
    const float dB1  = decBih[j0 + 1] + decBhh[j0 + 1];
    const float fcb0 = fcB[0];

    // h0 = 0
    for (int i = tid; i < RPB * HID; i += 256)
        (&hbuf[0][0][0])[i] = 0.f;
    __syncthreads();

    int cur = 0;
    for (int t = 0; t < SEQ + OUTT; t++) {
        const bool enc = (t < SEQ);
        const float* __restrict__ Wt = enc ? WtEnc : WtDec;
        const float* __restrict__ hc = &hbuf[cur][0][0];

        float acc0[RPB], acc1[RPB];
        #pragma unroll
        for (int r = 0; r < RPB; r++) { acc0[r] = 0.f; acc1[r] = 0.f; }

        // ---- GEMM: acc[r][{0,1}] = sum_k h[r][k] * Wt[k][j0+{0,1}] ----
        // software-pipelined in 8-k halves: w for next half loads during FMAs
        float2 wA[8], wB[8];
        #pragma unroll
        for (int kk = 0; kk < 8; kk++)
            wA[kk] = *(const float2*)&Wt[(size_t)kk * HID + j0];

        for (int k = 0; k < HID; k += 16) {
            // prefetch second half's weights
            #pragma unroll
            for (int kk = 0; kk < 8; kk++)
                wB[kk] = *(const float2*)&Wt[(size_t)(k + 8 + kk) * HID + j0];

            {   // compute half 1 (k .. k+7) with wA
                float a[RPB][8];
                #pragma unroll
                for (int r = 0; r < RPB; r++) {
                    float4 v0 = *(const float4*)&hc[r * HID + k];
                    float4 v1 = *(const float4*)&hc[r * HID + k + 4];
                    a[r][0]=v0.x; a[r][1]=v0.y; a[r][2]=v0.z; a[r][3]=v0.w;
                    a[r][4]=v1.x; a[r][5]=v1.y; a[r][6]=v1.z; a[r][7]=v1.w;
                }
                #pragma unroll
                for (int kk = 0; kk < 8; kk++)
                    #pragma unroll
                    for (int r = 0; r < RPB; r++) {
                        acc0[r] = fmaf(a[r][kk], wA[kk].x, acc0[r]);
                        acc1[r] = fmaf(a[r][kk], wA[kk].y, acc1[r]);
                    }
            }

            // prefetch next iteration's first-half weights
            if (k + 16 < HID) {
                #pragma unroll
                for (int kk = 0; kk < 8; kk++)
                    wA[kk] = *(const float2*)&Wt[(size_t)(k + 16 + kk) * HID + j0];
            }

            {   // compute half 2 (k+8 .. k+15) with wB
                float a[RPB][8];
                #pragma unroll
                for (int r = 0; r < RPB; r++) {
                    float4 v0 = *(const float4*)&hc[r * HID + k + 8];
                    float4 v1 = *(const float4*)&hc[r * HID + k + 12];
                    a[r][0]=v0.x; a[r][1]=v0.y; a[r][2]=v0.z; a[r][3]=v0.w;
                    a[r][4]=v1.x; a[r][5]=v1.y; a[r][6]=v1.z; a[r][7]=v1.w;
                }
                #pragma unroll
                for (int kk = 0; kk < 8; kk++)
                    #pragma unroll
                    for (int r = 0; r < RPB; r++) {
                        acc0[r] = fmaf(a[r][kk], wB[kk].x, acc0[r]);
                        acc1[r] = fmaf(a[r][kk], wB[kk].y, acc1[r]);
                    }
            }
        }

        // ---- epilogue: + inp*Wih + biases, tanh, store to LDS ----
        float inp[RPB];
        if (enc) {
            #pragma unroll
            for (int r = 0; r < RPB; r++)
                inp[r] = x[(size_t)(row0 + r) * SEQ + t];
        } else if (t == SEQ) {
            #pragma unroll
            for (int r = 0; r < RPB; r++)
                inp[r] = x[(size_t)(row0 + r) * SEQ + (SEQ - 1)];
        } else {
            #pragma unroll
            for (int r = 0; r < RPB; r++)
                inp[r] = dec_in_s[r];
        }
        const float wi0 = enc ? eWi0 : dWi0, wi1 = enc ? eWi1 : dWi1;
        const float b0  = enc ? eB0  : dB0,  b1  = enc ? eB1  : dB1;

        const int nxt = cur ^ 1;
        #pragma unroll
        for (int r = 0; r < RPB; r++) {
            float v0 = tanhf(acc0[r] + inp[r] * wi0 + b0);
            float v1 = tanhf(acc1[r] + inp[r] * wi1 + b1);
            *(float2*)&hbuf[nxt][r][j0] = make_float2(v0, v1);
        }
        __syncthreads();   // h_next complete & visible

        // ---- decoder FC: out[r] = dot(h_next[r], fcW) + fcb ----
        if (!enc) {
            const int wv = tid >> 6, lane = tid & 63;
            #pragma unroll
            for (int rr = 0; rr < 2; rr++) {
                const int r = wv * 2 + rr;
                const float* hr = &hbuf[nxt][r][0];
                float s = 0.f;
                #pragma unroll
                for (int m = 0; m < HID / 64; m++)
                    s = fmaf(hr[lane + 64 * m], fcW[lane + 64 * m], s);
                #pragma unroll
                for (int off = 32; off > 0; off >>= 1)
                    s += __shfl_down(s, off, 64);
                if (lane == 0) {
                    float o = s + fcb0;
                    dec_in_s[r] = o;
                    out[(size_t)(row0 + r) * OUTT + (t - SEQ)] = o;
                }
            }
            __syncthreads();   // dec_in_s visible for next step
        }
        cur = nxt;
    }
}

extern "C" void kernel_launch(void* const* d_in, const int* in_sizes, int n_in,
                              void* d_out, int out_size, void* d_ws, size_t ws_size,
                              hipStream_t stream)
{
    const float* x        = (const float*)d_in[0];
    const float* enc_Wih  = (const float*)d_in[1];
    const float* enc_Whh  = (const float*)d_in[2];
    const float* enc_bih  = (const float*)d_in[3];
    const float* enc_bhh  = (const float*)d_in[4];
    const float* dec_Wih  = (const float*)d_in[5];
    const float* dec_Whh  = (const float*)d_in[6];
    const float* dec_bih  = (const float*)d_in[7];
    const float* dec_bhh  = (const float*)d_in[8];
    const float* fc_W     = (const float*)d_in[9];
    const float* fc_b     = (const float*)d_in[10];
    float* out = (float*)d_out;

    float* WtEnc = (float*)d_ws;                          // 1 MB
    float* WtDec = (float*)((char*)d_ws + (size_t)HID * HID * sizeof(float));

    dim3 tg(HID / 32, HID / 32);  // (16,16)
    transpose_w<<<tg, 256, 0, stream>>>(enc_Whh, WtEnc);
    transpose_w<<<tg, 256, 0, stream>>>(dec_Whh, WtDec);

    rnn_persist<<<NBLK, 256, 0, stream>>>(
        x, WtEnc, WtDec,
        enc_Wih, enc_bih, enc_bhh,
        dec_Wih, dec_bih, dec_bhh,
        fc_W, fc_b, out);
}

// Round 3
// 3638.713 us; speedup vs baseline: 1.2747x; 1.0371x over previous
//
#include <hip/hip_runtime.h>
#include <math.h>

#define BATCH 2048
#define SEQ   128
#define HID   512
#define OUTT  24
#define RPB   8            // batch rows per block
#define NBLK  (BATCH/RPB)  // 256 blocks
#define TPB   512          // 8 waves = 2 per SIMD

// Pack W[j][k] (HIDxHID row-major) -> Wp[k/4][j][4] so thread j loads
// w[k..k+3] as one float4, coalesced across lanes (consecutive j).
__global__ __launch_bounds__(256) void pack_w(const float* __restrict__ W,
                                              float* __restrict__ Wp)
{
    int idx = blockIdx.x * 256 + threadIdx.x;   // 0 .. HID*HID-1
    int j = idx >> 9;        // row of W
    int k = idx & (HID - 1);
    float v = W[idx];
    Wp[((size_t)(k >> 2) * HID + j) * 4 + (k & 3)] = v;
}

__device__ __forceinline__ float4 ldW(const float* __restrict__ Wp, int k, int j)
{
    return *(const float4*)&Wp[((size_t)(k >> 2) * HID + j) * 4];
}

// Persistent: block owns RPB batch rows for all 152 steps. h ping-pongs in
// LDS (broadcast reads); weights stream from L2 (disjoint per wave).
__global__ __launch_bounds__(TPB, 2) void rnn_persist(
    const float* __restrict__ x,        // [BATCH][SEQ]
    const float* __restrict__ WpEnc,    // packed
    const float* __restrict__ WpDec,    // packed
    const float* __restrict__ encWih,
    const float* __restrict__ encBih,
    const float* __restrict__ encBhh,
    const float* __restrict__ decWih,
    const float* __restrict__ decBih,
    const float* __restrict__ decBhh,
    const float* __restrict__ fcW,
    const float* __restrict__ fcB,
    float* __restrict__ out)            // [BATCH][OUTT]
{
    __shared__ float hbuf[2][RPB][HID];   // 32 KB ping-pong
    __shared__ float dec_in_s[RPB];

    const int tid  = threadIdx.x;
    const int j    = tid;                 // each thread owns one hidden unit
    const int row0 = blockIdx.x * RPB;

    const float eWi  = encWih[j];
    const float eB   = encBih[j] + encBhh[j];
    const float dWi  = decWih[j];
    const float dB   = decBih[j] + decBhh[j];
    const float fcb0 = fcB[0];

    for (int i = tid; i < RPB * HID; i += TPB)
        (&hbuf[0][0][0])[i] = 0.f;
    __syncthreads();

    int cur = 0;
    for (int t = 0; t < SEQ + OUTT; t++) {
        const bool enc = (t < SEQ);
        const float* __restrict__ Wp = enc ? WpEnc : WpDec;
        const float* __restrict__ hc = &hbuf[cur][0][0];

        float acc[RPB];
        #pragma unroll
        for (int r = 0; r < RPB; r++) acc[r] = 0.f;

        // ---- k-loop: acc[r] += sum_k h[r][k] * W[j][k] ----
        // A/B phase double buffer, named registers, guarded wrap prefetch.
        float4 wA = ldW(Wp, 0, j);
        float4 hA0 = *(const float4*)&hc[0*HID], hA1 = *(const float4*)&hc[1*HID];
        float4 hA2 = *(const float4*)&hc[2*HID], hA3 = *(const float4*)&hc[3*HID];
        float4 hA4 = *(const float4*)&hc[4*HID], hA5 = *(const float4*)&hc[5*HID];
        float4 hA6 = *(const float4*)&hc[6*HID], hA7 = *(const float4*)&hc[7*HID];

        for (int k0 = 0; k0 < HID; k0 += 8) {
            const int k1 = k0 + 4;
            const int k2 = (k0 + 8 < HID) ? (k0 + 8) : 0;  // uniform select

            // prefetch phase B (k1)
            float4 wB  = ldW(Wp, k1, j);
            float4 hB0 = *(const float4*)&hc[0*HID + k1], hB1 = *(const float4*)&hc[1*HID + k1];
            float4 hB2 = *(const float4*)&hc[2*HID + k1], hB3 = *(const float4*)&hc[3*HID + k1];
            float4 hB4 = *(const float4*)&hc[4*HID + k1], hB5 = *(const float4*)&hc[5*HID + k1];
            float4 hB6 = *(const float4*)&hc[6*HID + k1], hB7 = *(const float4*)&hc[7*HID + k1];

            // compute phase A (k0)
            acc[0] = fmaf(hA0.x, wA.x, acc[0]); acc[0] = fmaf(hA0.y, wA.y, acc[0]);
            acc[0] = fmaf(hA0.z, wA.z, acc[0]); acc[0] = fmaf(hA0.w, wA.w, acc[0]);
            acc[1] = fmaf(hA1.x, wA.x, acc[1]); acc[1] = fmaf(hA1.y, wA.y, acc[1]);
            acc[1] = fmaf(hA1.z, wA.z, acc[1]); acc[1] = fmaf(hA1.w, wA.w, acc[1]);
            acc[2] = fmaf(hA2.x, wA.x, acc[2]); acc[2] = fmaf(hA2.y, wA.y, acc[2]);
            acc[2] = fmaf(hA2.z, wA.z, acc[2]); acc[2] = fmaf(hA2.w, wA.w, acc[2]);
            acc[3] = fmaf(hA3.x, wA.x, acc[3]); acc[3] = fmaf(hA3.y, wA.y, acc[3]);
            acc[3] = fmaf(hA3.z, wA.z, acc[3]); acc[3] = fmaf(hA3.w, wA.w, acc[3]);
            acc[4] = fmaf(hA4.x, wA.x, acc[4]); acc[4] = fmaf(hA4.y, wA.y, acc[4]);
            acc[4] = fmaf(hA4.z, wA.z, acc[4]); acc[4] = fmaf(hA4.w, wA.w, acc[4]);
            acc[5] = fmaf(hA5.x, wA.x, acc[5]); acc[5] = fmaf(hA5.y, wA.y, acc[5]);
            acc[5] = fmaf(hA5.z, wA.z, acc[5]); acc[5] = fmaf(hA5.w, wA.w, acc[5]);
            acc[6] = fmaf(hA6.x, wA.x, acc[6]); acc[6] = fmaf(hA6.y, wA.y, acc[6]);
            acc[6] = fmaf(hA6.z, wA.z, acc[6]); acc[6] = fmaf(hA6.w, wA.w, acc[6]);
            acc[7] = fmaf(hA7.x, wA.x, acc[7]); acc[7] = fmaf(hA7.y, wA.y, acc[7]);
            acc[7] = fmaf(hA7.z, wA.z, acc[7]); acc[7] = fmaf(hA7.w, wA.w, acc[7]);

            // prefetch phase A of next iter (k2; wraps to 0 on last, harmless)
            wA  = ldW(Wp, k2, j);
            hA0 = *(const float4*)&hc[0*HID + k2]; hA1 = *(const float4*)&hc[1*HID + k2];
            hA2 = *(const float4*)&hc[2*HID + k2]; hA3 = *(const float4*)&hc[3*HID + k2];
            hA4 = *(const float4*)&hc[4*HID + k2]; hA5 = *(const float4*)&hc[5*HID + k2];
            hA6 = *(const float4*)&hc[6*HID + k2]; hA7 = *(const float4*)&hc[7*HID + k2];

            // compute phase B (k1)
            acc[0] = fmaf(hB0.x, wB.x, acc[0]); acc[0] = fmaf(hB0.y, wB.y, acc[0]);
            acc[0] = fmaf(hB0.z, wB.z, acc[0]); acc[0] = fmaf(hB0.w, wB.w, acc[0]);
            acc[1] = fmaf(hB1.x, wB.x, acc[1]); acc[1] = fmaf(hB1.y, wB.y, acc[1]);
            acc[1] = fmaf(hB1.z, wB.z, acc[1]); acc[1] = fmaf(hB1.w, wB.w, acc[1]);
            acc[2] = fmaf(hB2.x, wB.x, acc[2]); acc[2] = fmaf(hB2.y, wB.y, acc[2]);
            acc[2] = fmaf(hB2.z, wB.z, acc[2]); acc[2] = fmaf(hB2.w, wB.w, acc[2]);
            acc[3] = fmaf(hB3.x, wB.x, acc[3]); acc[3] = fmaf(hB3.y, wB.y, acc[3]);
            acc[3] = fmaf(hB3.z, wB.z, acc[3]); acc[3] = fmaf(hB3.w, wB.w, acc[3]);
            acc[4] = fmaf(hB4.x, wB.x, acc[4]); acc[4] = fmaf(hB4.y, wB.y, acc[4]);
            acc[4] = fmaf(hB4.z, wB.z, acc[4]); acc[4] = fmaf(hB4.w, wB.w, acc[4]);
            acc[5] = fmaf(hB5.x, wB.x, acc[5]); acc[5] = fmaf(hB5.y, wB.y, acc[5]);
            acc[5] = fmaf(hB5.z, wB.z, acc[5]); acc[5] = fmaf(hB5.w, wB.w, acc[5]);
            acc[6] = fmaf(hB6.x, wB.x, acc[6]); acc[6] = fmaf(hB6.y, wB.y, acc[6]);
            acc[6] = fmaf(hB6.z, wB.z, acc[6]); acc[6] = fmaf(hB6.w, wB.w, acc[6]);
            acc[7] = fmaf(hB7.x, wB.x, acc[7]); acc[7] = fmaf(hB7.y, wB.y, acc[7]);
            acc[7] = fmaf(hB7.z, wB.z, acc[7]); acc[7] = fmaf(hB7.w, wB.w, acc[7]);
        }

        // ---- epilogue ----
        float inp[RPB];
        if (enc) {
            #pragma unroll
            for (int r = 0; r < RPB; r++)
                inp[r] = x[(size_t)(row0 + r) * SEQ + t];
        } else if (t == SEQ) {
            #pragma unroll
            for (int r = 0; r < RPB; r++)
                inp[r] = x[(size_t)(row0 + r) * SEQ + (SEQ - 1)];
        } else {
            #pragma unroll
            for (int r = 0; r < RPB; r++)
                inp[r] = dec_in_s[r];
        }
        const float wi = enc ? eWi : dWi;
        const float bb = enc ? eB  : dB;

        const int nxt = cur ^ 1;
        #pragma unroll
        for (int r = 0; r < RPB; r++)
            hbuf[nxt][r][j] = tanhf(acc[r] + inp[r] * wi + bb);
        __syncthreads();   // h_next complete

        if (!enc) {
            // wave w reduces row w (8 waves, 8 rows)
            const int wv = tid >> 6, lane = tid & 63;
            const float* hr = &hbuf[nxt][wv][0];
            float s = 0.f;
            #pragma unroll
            for (int m = 0; m < HID / 64; m++)
                s = fmaf(hr[lane + 64 * m], fcW[lane + 64 * m], s);
            #pragma unroll
            for (int off = 32; off > 0; off >>= 1)
                s += __shfl_down(s, off, 64);
            if (lane == 0) {
                float o = s + fcb0;
                dec_in_s[wv] = o;
                out[(size_t)(row0 + wv) * OUTT + (t - SEQ)] = o;
            }
            __syncthreads();   // dec_in_s visible
        }
        cur = nxt;
    }
}

extern "C" void kernel_launch(void* const* d_in, const int* in_sizes, int n_in,
                              void* d_out, int out_size, void* d_ws, size_t ws_size,
                              hipStream_t stream)
{
    const float* x        = (const float*)d_in[0];
    const float* enc_Wih  = (const float*)d_in[1];
    const float* enc_Whh  = (const float*)d_in[2];
    const float* enc_bih  = (const float*)d_in[3];
    const float* enc_bhh  = (const float*)d_in[4];
    const float* dec_Wih  = (const float*)d_in[5];
    const float* dec_Whh  = (const float*)d_in[6];
    const float* dec_bih  = (const float*)d_in[7];
    const float* dec_bhh  = (const float*)d_in[8];
    const float* fc_W     = (const float*)d_in[9];
    const float* fc_b     = (const float*)d_in[10];
    float* out = (float*)d_out;

    float* WpEnc = (float*)d_ws;
    float* WpDec = (float*)((char*)d_ws + (size_t)HID * HID * sizeof(float));

    pack_w<<<HID * HID / 256, 256, 0, stream>>>(enc_Whh, WpEnc);
    pack_w<<<HID * HID / 256, 256, 0, stream>>>(dec_Whh, WpDec);

    rnn_persist<<<NBLK, TPB, 0, stream>>>(
        x, WpEnc, WpDec,
        enc_Wih, enc_bih, enc_bhh,
        dec_Wih, dec_bih, dec_bhh,
        fc_W, fc_b, out);
}

// Round 4
// 1499.528 us; speedup vs baseline: 3.0931x; 2.4266x over previous
//
#include <hip/hip_runtime.h>
#include <hip/hip_bf16.h>
#include <math.h>

#define BATCH 2048
#define SEQ   128
#define HID   512
#define OUTT  24
#define RPB   16              // batch rows per block (MFMA M)
#define NBLK  (BATCH/RPB)     // 128 blocks
#define TPB   512             // 8 waves
#define NTW   4               // n-tiles per wave (32 tiles / 8 waves)
#define KTN   (HID/32)        // 16 k-tiles
#define NTILES (HID/16)       // 32 n-tiles

typedef short short8 __attribute__((ext_vector_type(8)));
typedef float floatx4 __attribute__((ext_vector_type(4)));

__device__ __forceinline__ short f2bf(float v) {
    __hip_bfloat16 b = __float2bfloat16(v);
    short s; __builtin_memcpy(&s, &b, 2); return s;
}
__device__ __forceinline__ float bf2f(short s) {
    __hip_bfloat16 b; __builtin_memcpy(&b, &s, 2);
    return __bfloat162float(b);
}

// Pack W[j][k] (row-major HIDxHID) into per-lane MFMA B-fragment layout,
// split into bf16 hi/lo:  frag[(kt*32+nt)*64 + lane][8] where lane holds
// B[k = kt*32 + (lane>>4)*8 + jj][n = nt*16 + (lane&15)] = W[n][k].
__global__ __launch_bounds__(256) void pack_wfrag(const float* __restrict__ W,
                                                  short* __restrict__ Hi,
                                                  short* __restrict__ Lo)
{
    int id   = blockIdx.x * 256 + threadIdx.x;   // 0 .. 32767
    int lane = id & 63;
    int nt   = (id >> 6) & 31;
    int kt   = id >> 11;
    int n  = nt * 16 + (lane & 15);
    int k0 = kt * 32 + (lane >> 4) * 8;
    const float* src = W + (size_t)n * HID + k0;
    short8 hv, lv;
    #pragma unroll
    for (int j = 0; j < 8; j++) {
        float v = src[j];
        short h = f2bf(v);
        float r = v - bf2f(h);
        hv[j] = h;
        lv[j] = f2bf(r);
    }
    *(short8*)&Hi[(size_t)id * 8] = hv;
    *(short8*)&Lo[(size_t)id * 8] = lv;
}

// A-layout LDS address for element (m, k):  (k>>5)*512 + ((k>>3)&3)*128 + m*8 + (k&7)
// => lane l reads its A-fragment for tile kt as one contiguous short8 at
//    kt*512 + (l>>4)*128 + (l&15)*8.
__global__ __launch_bounds__(TPB, 1) void rnn_persist(
    const float* __restrict__ x,
    const short* __restrict__ WEh, const short* __restrict__ WEl,
    const short* __restrict__ WDh, const short* __restrict__ WDl,
    const float* __restrict__ encWih, const float* __restrict__ encBih,
    const float* __restrict__ encBhh,
    const float* __restrict__ decWih, const float* __restrict__ decBih,
    const float* __restrict__ decBhh,
    const float* __restrict__ fcW, const float* __restrict__ fcB,
    float* __restrict__ out)
{
    __shared__ short Ahi[2][KTN * 512];   // 2 x 16 KB
    __shared__ short Alo[2][KTN * 512];   // 2 x 16 KB
    __shared__ float dec_in_s[RPB];

    const int tid  = threadIdx.x;
    const int lane = tid & 63;
    const int wv   = tid >> 6;
    const int row0 = blockIdx.x * RPB;
    const int c    = lane & 15;   // n-within-tile; also m for A-frag read
    const int q    = lane >> 4;   // quad
    const int mB   = q * 4;       // C-frag row base

    // hoist per-ntile epilogue constants
    float eWi[NTW], eBb[NTW], dWi[NTW], dBb[NTW];
    #pragma unroll
    for (int i = 0; i < NTW; i++) {
        int n = (wv * NTW + i) * 16 + c;
        eWi[i] = encWih[n]; eBb[i] = encBih[n] + encBhh[n];
        dWi[i] = decWih[n]; dBb[i] = decBih[n] + decBhh[n];
    }
    const float fcb0 = fcB[0];

    // h0 = 0
    for (int i = tid; i < KTN * 512 / 2; i += TPB) {
        ((int*)Ahi[0])[i] = 0;
        ((int*)Alo[0])[i] = 0;
    }
    __syncthreads();

    const int ldsAoff = q * 128 + c * 8;

    int cur = 0;
    for (int t = 0; t < SEQ + OUTT; t++) {
        const bool enc = (t < SEQ);
        const short* __restrict__ Bh = enc ? WEh : WDh;
        const short* __restrict__ Bl = enc ? WEl : WDl;
        const short* Ah = Ahi[cur];
        const short* Al = Alo[cur];

        floatx4 acc[NTW];
        #pragma unroll
        for (int i = 0; i < NTW; i++) acc[i] = (floatx4){0.f, 0.f, 0.f, 0.f};

        for (int kt = 0; kt < KTN; kt++) {
            short8 ah = *(const short8*)&Ah[kt * 512 + ldsAoff];
            short8 al = *(const short8*)&Al[kt * 512 + ldsAoff];
            #pragma unroll
            for (int i = 0; i < NTW; i++) {
                int nt = wv * NTW + i;
                size_t bo = ((size_t)(kt * NTILES + nt) * 64 + lane) * 8;
                short8 bh = *(const short8*)&Bh[bo];
                short8 bl = *(const short8*)&Bl[bo];
                acc[i] = __builtin_amdgcn_mfma_f32_16x16x32_bf16(ah, bh, acc[i], 0, 0, 0);
                acc[i] = __builtin_amdgcn_mfma_f32_16x16x32_bf16(ah, bl, acc[i], 0, 0, 0);
                acc[i] = __builtin_amdgcn_mfma_f32_16x16x32_bf16(al, bh, acc[i], 0, 0, 0);
            }
        }

        // ---- epilogue: v = tanh(acc + inp*Wih + bias); split; store A[nxt] ----
        float inp[4];
        if (enc) {
            #pragma unroll
            for (int r = 0; r < 4; r++)
                inp[r] = x[(size_t)(row0 + mB + r) * SEQ + t];
        } else if (t == SEQ) {
            #pragma unroll
            for (int r = 0; r < 4; r++)
                inp[r] = x[(size_t)(row0 + mB + r) * SEQ + (SEQ - 1)];
        } else {
            #pragma unroll
            for (int r = 0; r < 4; r++)
                inp[r] = dec_in_s[mB + r];
        }

        const int nxt = cur ^ 1;
        #pragma unroll
        for (int i = 0; i < NTW; i++) {
            int nt = wv * NTW + i;
            int k  = nt * 16 + c;            // this n is next step's k
            int base = (k >> 5) * 512 + ((k >> 3) & 3) * 128 + (k & 7);
            float wi = enc ? eWi[i] : dWi[i];
            float bb = enc ? eBb[i] : dBb[i];
            #pragma unroll
            for (int r = 0; r < 4; r++) {
                float v  = tanhf(acc[i][r] + inp[r] * wi + bb);
                short hv = f2bf(v);
                float rs = v - bf2f(hv);
                int m = mB + r;
                Ahi[nxt][base + m * 8] = hv;
                Alo[nxt][base + m * 8] = f2bf(rs);
            }
        }
        __syncthreads();   // A[nxt] complete

        if (!enc) {
            // FC: wave wv reduces rows 2wv, 2wv+1 from A[nxt]
            #pragma unroll
            for (int rr = 0; rr < 2; rr++) {
                int m = wv * 2 + rr;
                float s = 0.f;
                #pragma unroll
                for (int ii = 0; ii < HID / 64; ii++) {
                    int k = ii * 64 + lane;
                    int a = (k >> 5) * 512 + ((k >> 3) & 3) * 128 + m * 8 + (k & 7);
                    float hvv = bf2f(Ahi[nxt][a]) + bf2f(Alo[nxt][a]);
                    s = fmaf(hvv, fcW[k], s);
                }
                #pragma unroll
                for (int off = 32; off > 0; off >>= 1)
                    s += __shfl_down(s, off, 64);
                if (lane == 0) {
                    float o = s + fcb0;
                    dec_in_s[m] = o;
                    out[(size_t)(row0 + m) * OUTT + (t - SEQ)] = o;
                }
            }
            __syncthreads();   // dec_in_s visible
        }
        cur = nxt;
    }
}

extern "C" void kernel_launch(void* const* d_in, const int* in_sizes, int n_in,
                              void* d_out, int out_size, void* d_ws, size_t ws_size,
                              hipStream_t stream)
{
    const float* x        = (const float*)d_in[0];
    const float* enc_Wih  = (const float*)d_in[1];
    const float* enc_Whh  = (const float*)d_in[2];
    const float* enc_bih  = (const float*)d_in[3];
    const float* enc_bhh  = (const float*)d_in[4];
    const float* dec_Wih  = (const float*)d_in[5];
    const float* dec_Whh  = (const float*)d_in[6];
    const float* dec_bih  = (const float*)d_in[7];
    const float* dec_bhh  = (const float*)d_in[8];
    const float* fc_W     = (const float*)d_in[9];
    const float* fc_b     = (const float*)d_in[10];
    float* out = (float*)d_out;

    const size_t wfrag = (size_t)HID * HID;   // elements per packed matrix
    short* WEh = (short*)d_ws;
    short* WEl = WEh + wfrag;
    short* WDh = WEl + wfrag;
    short* WDl = WDh + wfrag;

    pack_wfrag<<<HID * HID / (256 * 8), 256, 0, stream>>>(enc_Whh, WEh, WEl);
    pack_wfrag<<<HID * HID / (256 * 8), 256, 0, stream>>>(dec_Whh, WDh, WDl);

    rnn_persist<<<NBLK, TPB, 0, stream>>>(
        x, WEh, WEl, WDh, WDl,
        enc_Wih, enc_bih, enc_bhh,
        dec_Wih, dec_bih, dec_bhh,
        fc_W, fc_b, out);
}

// Round 5
// 908.054 us; speedup vs baseline: 5.1078x; 1.6514x over previous
//
#include <hip/hip_runtime.h>
#include <math.h>

#define BATCH 2048
#define SEQ   128
#define HID   512
#define OUTT  24
#define RPB   16              // batch rows per block (MFMA M)
#define NBLK  (BATCH/RPB)     // 128 blocks
#define TPB   512             // 8 waves
#define NTW   4               // n-tiles per wave (32 tiles / 8 waves)
#define KTN   (HID/32)        // 16 k-tiles
#define NTILES (HID/16)       // 32 n-tiles

typedef _Float16 half8 __attribute__((ext_vector_type(8)));
typedef float   floatx4 __attribute__((ext_vector_type(4)));

// Pack W[j][k] (row-major HIDxHID, fp32) into per-lane MFMA B-fragment layout,
// single fp16: frag[(kt*32+nt)*64 + lane][8] with lane holding
// B[k = kt*32 + (lane>>4)*8 + jj][n = nt*16 + (lane&15)] = W[n][k].
__global__ __launch_bounds__(256) void pack_wfrag(const float* __restrict__ W,
                                                  _Float16* __restrict__ Bw)
{
    int id   = blockIdx.x * 256 + threadIdx.x;   // 0 .. 32767 frag-lanes
    int lane = id & 63;
    int nt   = (id >> 6) & 31;
    int kt   = id >> 11;
    int n  = nt * 16 + (lane & 15);
    int k0 = kt * 32 + (lane >> 4) * 8;
    const float* src = W + (size_t)n * HID + k0;
    half8 v;
    #pragma unroll
    for (int j = 0; j < 8; j++) v[j] = (_Float16)src[j];
    *(half8*)&Bw[(size_t)id * 8] = v;
}

// A-layout LDS address for element (m, k): (k>>5)*512 + ((k>>3)&3)*128 + m*8 + (k&7)
// => lane l reads its A-fragment for k-tile kt contiguously at
//    kt*512 + (l>>4)*128 + (l&15)*8.
__global__ __launch_bounds__(TPB, 1) void rnn_persist(
    const float* __restrict__ x,
    const _Float16* __restrict__ BwE,   // packed enc Whh (fp16)
    const _Float16* __restrict__ BwD,   // packed dec Whh (fp16)
    const float* __restrict__ encWih, const float* __restrict__ encBih,
    const float* __restrict__ encBhh,
    const float* __restrict__ decWih, const float* __restrict__ decBih,
    const float* __restrict__ decBhh,
    const float* __restrict__ fcW, const float* __restrict__ fcB,
    float* __restrict__ out)
{
    __shared__ _Float16 Ahi[2][KTN * 512];   // 2 x 16 KB (h fp16 hi)
    __shared__ _Float16 Alo[2][KTN * 512];   // 2 x 16 KB (h fp16 residual)
    __shared__ float dec_in_s[RPB];

    const int tid  = threadIdx.x;
    const int lane = tid & 63;
    const int wv   = tid >> 6;
    const int row0 = blockIdx.x * RPB;
    const int c    = lane & 15;   // n-within-tile (B); m (A-frag)
    const int q    = lane >> 4;   // quad
    const int mB   = q * 4;       // C-frag row base

    // hoisted epilogue constants (per owned n)
    float eWi[NTW], eBb[NTW], dWi[NTW], dBb[NTW];
    #pragma unroll
    for (int i = 0; i < NTW; i++) {
        int n = (wv * NTW + i) * 16 + c;
        eWi[i] = encWih[n]; eBb[i] = encBih[n] + encBhh[n];
        dWi[i] = decWih[n]; dBb[i] = decBih[n] + decBhh[n];
    }
    const float fcb0 = fcB[0];

    // h0 = 0
    for (int i = tid; i < KTN * 512 / 2; i += TPB) {
        ((int*)Ahi[0])[i] = 0;
        ((int*)Alo[0])[i] = 0;
    }
    __syncthreads();

    const int ldsAoff = q * 128 + c * 8;
    // B frag element offsets: nt stride = 64*8 = 512; kt stride = 32*64*8 = 16384
    const size_t bbase = ((size_t)(wv * NTW) * 64 + lane) * 8;

    int cur = 0;
    for (int t = 0; t < SEQ + OUTT; t++) {
        const bool enc = (t < SEQ);
        const _Float16* __restrict__ Bw = enc ? BwE : BwD;
        const _Float16* Ah = Ahi[cur];
        const _Float16* Al = Alo[cur];

        floatx4 acc[NTW];
        #pragma unroll
        for (int i = 0; i < NTW; i++) acc[i] = (floatx4){0.f, 0.f, 0.f, 0.f};

        // prime B prefetch for kt=0
        half8 b0 = *(const half8*)&Bw[bbase];
        half8 b1 = *(const half8*)&Bw[bbase + 512];
        half8 b2 = *(const half8*)&Bw[bbase + 1024];
        half8 b3 = *(const half8*)&Bw[bbase + 1536];

        #pragma unroll
        for (int kt = 0; kt < KTN; kt++) {
            half8 ah = *(const half8*)&Ah[kt * 512 + ldsAoff];
            half8 al = *(const half8*)&Al[kt * 512 + ldsAoff];

            // prefetch next kt's B fragments (dead on last iter, folded at compile time)
            half8 n0 = b0, n1 = b1, n2 = b2, n3 = b3;
            if (kt + 1 < KTN) {
                size_t nb = bbase + (size_t)(kt + 1) * 16384;
                n0 = *(const half8*)&Bw[nb];
                n1 = *(const half8*)&Bw[nb + 512];
                n2 = *(const half8*)&Bw[nb + 1024];
                n3 = *(const half8*)&Bw[nb + 1536];
            }

            acc[0] = __builtin_amdgcn_mfma_f32_16x16x32_f16(ah, b0, acc[0], 0, 0, 0);
            acc[0] = __builtin_amdgcn_mfma_f32_16x16x32_f16(al, b0, acc[0], 0, 0, 0);
            acc[1] = __builtin_amdgcn_mfma_f32_16x16x32_f16(ah, b1, acc[1], 0, 0, 0);
            acc[1] = __builtin_amdgcn_mfma_f32_16x16x32_f16(al, b1, acc[1], 0, 0, 0);
            acc[2] = __builtin_amdgcn_mfma_f32_16x16x32_f16(ah, b2, acc[2], 0, 0, 0);
            acc[2] = __builtin_amdgcn_mfma_f32_16x16x32_f16(al, b2, acc[2], 0, 0, 0);
            acc[3] = __builtin_amdgcn_mfma_f32_16x16x32_f16(ah, b3, acc[3], 0, 0, 0);
            acc[3] = __builtin_amdgcn_mfma_f32_16x16x32_f16(al, b3, acc[3], 0, 0, 0);

            b0 = n0; b1 = n1; b2 = n2; b3 = n3;
        }

        // ---- epilogue: v = tanh(acc + inp*Wih + bias); fp16-split; store A[nxt] ----
        float inp[4];
        if (enc) {
            #pragma unroll
            for (int r = 0; r < 4; r++)
                inp[r] = x[(size_t)(row0 + mB + r) * SEQ + t];
        } else if (t == SEQ) {
            #pragma unroll
            for (int r = 0; r < 4; r++)
                inp[r] = x[(size_t)(row0 + mB + r) * SEQ + (SEQ - 1)];
        } else {
            #pragma unroll
            for (int r = 0; r < 4; r++)
                inp[r] = dec_in_s[mB + r];
        }

        const int nxt = cur ^ 1;
        #pragma unroll
        for (int i = 0; i < NTW; i++) {
            int nt = wv * NTW + i;
            int k  = nt * 16 + c;            // this n is next step's k
            int base = (k >> 5) * 512 + ((k >> 3) & 3) * 128 + (k & 7);
            float wi = enc ? eWi[i] : dWi[i];
            float bb = enc ? eBb[i] : dBb[i];
            #pragma unroll
            for (int r = 0; r < 4; r++) {
                float v = tanhf(acc[i][r] + inp[r] * wi + bb);
                _Float16 hh = (_Float16)v;
                float rs = v - (float)hh;
                int m = mB + r;
                Ahi[nxt][base + m * 8] = hh;
                Alo[nxt][base + m * 8] = (_Float16)rs;
            }
        }
        __syncthreads();   // A[nxt] complete

        if (!enc) {
            // FC: wave wv reduces rows 2wv, 2wv+1 from A[nxt]
            #pragma unroll
            for (int rr = 0; rr < 2; rr++) {
                int m = wv * 2 + rr;
                float s = 0.f;
                #pragma unroll
                for (int ii = 0; ii < HID / 64; ii++) {
                    int k = ii * 64 + lane;
                    int a = (k >> 5) * 512 + ((k >> 3) & 3) * 128 + m * 8 + (k & 7);
                    float hvv = (float)Ahi[nxt][a] + (float)Alo[nxt][a];
                    s = fmaf(hvv, fcW[k], s);
                }
                #pragma unroll
                for (int off = 32; off > 0; off >>= 1)
                    s += __shfl_down(s, off, 64);
                if (lane == 0) {
                    float o = s + fcb0;
                    dec_in_s[m] = o;
                    out[(size_t)(row0 + m) * OUTT + (t - SEQ)] = o;
                }
            }
            __syncthreads();   // dec_in_s visible
        }
        cur = nxt;
    }
}

extern "C" void kernel_launch(void* const* d_in, const int* in_sizes, int n_in,
                              void* d_out, int out_size, void* d_ws, size_t ws_size,
                              hipStream_t stream)
{
    const float* x        = (const float*)d_in[0];
    const float* enc_Wih  = (const float*)d_in[1];
    const float* enc_Whh  = (const float*)d_in[2];
    const float* enc_bih  = (const float*)d_in[3];
    const float* enc_bhh  = (const float*)d_in[4];
    const float* dec_Wih  = (const float*)d_in[5];
    const float* dec_Whh  = (const float*)d_in[6];
    const float* dec_bih  = (const float*)d_in[7];
    const float* dec_bhh  = (const float*)d_in[8];
    const float* fc_W     = (const float*)d_in[9];
    const float* fc_b     = (const float*)d_in[10];
    float* out = (float*)d_out;

    const size_t wfrag = (size_t)HID * HID;   // elements per packed matrix
    _Float16* BwE = (_Float16*)d_ws;
    _Float16* BwD = BwE + wfrag;

    pack_wfrag<<<HID * HID / (256 * 8), 256, 0, stream>>>(enc_Whh, BwE);
    pack_wfrag<<<HID * HID / (256 * 8), 256, 0, stream>>>(dec_Whh, BwD);

    rnn_persist<<<NBLK, TPB, 0, stream>>>(
        x, BwE, BwD,
        enc_Wih, enc_bih, enc_bhh,
        dec_Wih, dec_bih, dec_bhh,
        fc_W, fc_b, out);
}

// Round 6
// 739.549 us; speedup vs baseline: 6.2715x; 1.2278x over previous
//
#include <hip/hip_runtime.h>
#include <math.h>

#define BATCH 2048
#define SEQ   128
#define HID   512
#define OUTT  24
#define RPB   16              // batch rows per block (MFMA M)
#define NBLK  (BATCH/RPB)     // 128 blocks
#define TPB   512             // 8 waves = 2/SIMD
#define NTW   4               // n-tiles per wave
#define KTN   (HID/32)        // 16 k-tiles
#define NTILES (HID/16)       // 32 n-tiles
#define HOLD_KT 9             // k-tiles held in registers (144 VGPR/lane)
#define STR_KT  (KTN - HOLD_KT)

typedef _Float16 half8 __attribute__((ext_vector_type(8)));
typedef float   floatx4 __attribute__((ext_vector_type(4)));

// fast tanh: 1 - 2/(e^{2x}+1), e^{2x} = 2^(x*2/ln2). Saturates correctly.
__device__ __forceinline__ float ftanh(float x) {
    float e = __builtin_amdgcn_exp2f(x * 2.885390081777927f);
    float r = __builtin_amdgcn_rcpf(e + 1.0f);
    return fmaf(-2.0f, r, 1.0f);
}

// Pack W[j][k] (row-major HIDxHID fp32) into per-lane MFMA B-fragment layout,
// fp16: frag[(kt*32+nt)*64 + lane][8]; lane holds
// B[k = kt*32 + (lane>>4)*8 + jj][n = nt*16 + (lane&15)] = W[n][k].
__global__ __launch_bounds__(256) void pack_wfrag(const float* __restrict__ W,
                                                  _Float16* __restrict__ Bw)
{
    int id   = blockIdx.x * 256 + threadIdx.x;
    int lane = id & 63;
    int nt   = (id >> 6) & 31;
    int kt   = id >> 11;
    int n  = nt * 16 + (lane & 15);
    int k0 = kt * 32 + (lane >> 4) * 8;
    const float* src = W + (size_t)n * HID + k0;
    half8 v;
    #pragma unroll
    for (int j = 0; j < 8; j++) v[j] = (_Float16)src[j];
    *(half8*)&Bw[(size_t)id * 8] = v;
}

// Swizzled A layout: el(m,k) = (k>>5)*512 + G*128 + ((m^G)<<3) + (k&7), G=(k>>3)&3.
// Reader lane (q,c), k-tile kt: contiguous aligned 16 B at kt*512 + q*128 + ((c^q)<<3).
__global__ __launch_bounds__(TPB, 2) void rnn_persist(
    const float* __restrict__ x,
    const _Float16* __restrict__ BwE,
    const _Float16* __restrict__ BwD,
    const float* __restrict__ encWih, const float* __restrict__ encBih,
    const float* __restrict__ encBhh,
    const float* __restrict__ decWih, const float* __restrict__ decBih,
    const float* __restrict__ decBhh,
    const float* __restrict__ fcW, const float* __restrict__ fcB,
    float* __restrict__ out)
{
    __shared__ _Float16 Ahi[2][KTN * 512];   // 2 x 16 KB
    __shared__ _Float16 Alo[2][KTN * 512];   // 2 x 16 KB
    __shared__ float    xs[RPB][SEQ];        // 8 KB
    __shared__ float    dec_in_s[RPB];

    const int tid  = threadIdx.x;
    const int lane = tid & 63;
    const int wv   = tid >> 6;
    const int row0 = blockIdx.x * RPB;
    const int c    = lane & 15;
    const int q    = lane >> 4;
    const int mB   = q * 4;

    // epilogue constants per owned n
    float eWi[NTW], eBb[NTW], dWi[NTW], dBb[NTW];
    #pragma unroll
    for (int i = 0; i < NTW; i++) {
        int n = (wv * NTW + i) * 16 + c;
        eWi[i] = encWih[n]; eBb[i] = encBih[n] + encBhh[n];
        dWi[i] = decWih[n]; dBb[i] = decBih[n] + decBhh[n];
    }
    const float fcb0 = fcB[0];

    // preload x block-slice into LDS (coalesced float4)
    {
        const float4* xg = (const float4*)(x + (size_t)row0 * SEQ);
        float4* xl = (float4*)&xs[0][0];
        if (tid < RPB * SEQ / 4) xl[tid] = xg[tid];
    }

    // h0 = 0
    for (int i = tid; i < KTN * 512 / 2; i += TPB) {
        ((int*)Ahi[0])[i] = 0;
        ((int*)Alo[0])[i] = 0;
    }
    __syncthreads();

    const int ldsAoff = q * 128 + ((c ^ q) << 3);
    const size_t bbase = (size_t)(wv * NTW) * 512 + (size_t)lane * 8;

    // ---- load held weight k-tiles into registers (encoder first) ----
    half8 wreg[HOLD_KT][NTW];
    #pragma unroll
    for (int kt = 0; kt < HOLD_KT; kt++)
        #pragma unroll
        for (int i = 0; i < NTW; i++)
            wreg[kt][i] = *(const half8*)&BwE[bbase + (size_t)kt * 16384 + i * 512];

    int cur = 0;
    for (int t = 0; t < SEQ + OUTT; t++) {
        const bool enc = (t < SEQ);
        const _Float16* __restrict__ Bw = enc ? BwE : BwD;
        const _Float16* Ah = Ahi[cur];
        const _Float16* Al = Alo[cur];

        if (t == SEQ) {   // one-time: swap held weights to decoder matrix
            #pragma unroll
            for (int kt = 0; kt < HOLD_KT; kt++)
                #pragma unroll
                for (int i = 0; i < NTW; i++)
                    wreg[kt][i] = *(const half8*)&BwD[bbase + (size_t)kt * 16384 + i * 512];
        }

        floatx4 acc[NTW];
        #pragma unroll
        for (int i = 0; i < NTW; i++) acc[i] = (floatx4){0.f, 0.f, 0.f, 0.f};

        // prime streamed-B prefetch (2 k-tiles deep) before held compute
        half8 bcur[NTW], bnxt[NTW];
        #pragma unroll
        for (int i = 0; i < NTW; i++) {
            bcur[i] = *(const half8*)&Bw[bbase + (size_t)HOLD_KT * 16384 + i * 512];
            bnxt[i] = *(const half8*)&Bw[bbase + (size_t)(HOLD_KT + 1) * 16384 + i * 512];
        }

        // held k-tiles: B from registers, zero memory traffic
        #pragma unroll
        for (int kt = 0; kt < HOLD_KT; kt++) {
            half8 ah = *(const half8*)&Ah[kt * 512 + ldsAoff];
            half8 al = *(const half8*)&Al[kt * 512 + ldsAoff];
            #pragma unroll
            for (int i = 0; i < NTW; i++)
                acc[i] = __builtin_amdgcn_mfma_f32_16x16x32_f16(ah, wreg[kt][i], acc[i], 0, 0, 0);
            #pragma unroll
            for (int i = 0; i < NTW; i++)
                acc[i] = __builtin_amdgcn_mfma_f32_16x16x32_f16(al, wreg[kt][i], acc[i], 0, 0, 0);
        }

        // streamed k-tiles with rolling 2-deep prefetch
        #pragma unroll
        for (int s = 0; s < STR_KT; s++) {
            const int kt = HOLD_KT + s;
            half8 bpre[NTW];
            if (s + 2 < STR_KT) {
                #pragma unroll
                for (int i = 0; i < NTW; i++)
                    bpre[i] = *(const half8*)&Bw[bbase + (size_t)(kt + 2) * 16384 + i * 512];
            }
            half8 ah = *(const half8*)&Ah[kt * 512 + ldsAoff];
            half8 al = *(const half8*)&Al[kt * 512 + ldsAoff];
            #pragma unroll
            for (int i = 0; i < NTW; i++)
                acc[i] = __builtin_amdgcn_mfma_f32_16x16x32_f16(ah, bcur[i], acc[i], 0, 0, 0);
            #pragma unroll
            for (int i = 0; i < NTW; i++)
                acc[i] = __builtin_amdgcn_mfma_f32_16x16x32_f16(al, bcur[i], acc[i], 0, 0, 0);
            #pragma unroll
            for (int i = 0; i < NTW; i++) {
                bcur[i] = bnxt[i];
                if (s + 2 < STR_KT) bnxt[i] = bpre[i];
            }
        }

        // ---- epilogue ----
        float inp[4];
        if (enc) {
            #pragma unroll
            for (int r = 0; r < 4; r++) inp[r] = xs[mB + r][t];
        } else if (t == SEQ) {
            #pragma unroll
            for (int r = 0; r < 4; r++) inp[r] = xs[mB + r][SEQ - 1];
        } else {
            #pragma unroll
            for (int r = 0; r < 4; r++) inp[r] = dec_in_s[mB + r];
        }

        const int nxt = cur ^ 1;
        #pragma unroll
        for (int i = 0; i < NTW; i++) {
            int nt = wv * NTW + i;
            int k  = nt * 16 + c;            // this n is next step's k
            int G  = (k >> 3) & 3;
            int base = (k >> 5) * 512 + G * 128 + (k & 7);
            float wi = enc ? eWi[i] : dWi[i];
            float bb = enc ? eBb[i] : dBb[i];
            #pragma unroll
            for (int r = 0; r < 4; r++) {
                float v = ftanh(acc[i][r] + inp[r] * wi + bb);
                _Float16 hh = (_Float16)v;
                float rs = v - (float)hh;
                int off = base + (((mB + r) ^ G) << 3);
                Ahi[nxt][off] = hh;
                Alo[nxt][off] = (_Float16)rs;
            }
        }
        __syncthreads();   // A[nxt] complete

        if (!enc) {
            // FC: wave wv reduces rows 2wv, 2wv+1
            #pragma unroll
            for (int rr = 0; rr < 2; rr++) {
                int m = wv * 2 + rr;
                float s = 0.f;
                #pragma unroll
                for (int ii = 0; ii < HID / 64; ii++) {
                    int k = ii * 64 + lane;
                    int G = (k >> 3) & 3;
                    int a = (k >> 5) * 512 + G * 128 + ((m ^ G) << 3) + (k & 7);
                    float hvv = (float)Ahi[nxt][a] + (float)Alo[nxt][a];
                    s = fmaf(hvv, fcW[k], s);
                }
                #pragma unroll
                for (int off = 32; off > 0; off >>= 1)
                    s += __shfl_down(s, off, 64);
                if (lane == 0) {
                    float o = s + fcb0;
                    dec_in_s[m] = o;
                    out[(size_t)(row0 + m) * OUTT + (t - SEQ)] = o;
                }
            }
            __syncthreads();
        }
        cur = nxt;
    }
}

extern "C" void kernel_launch(void* const* d_in, const int* in_sizes, int n_in,
                              void* d_out, int out_size, void* d_ws, size_t ws_size,
                              hipStream_t stream)
{
    const float* x        = (const float*)d_in[0];
    const float* enc_Wih  = (const float*)d_in[1];
    const float* enc_Whh  = (const float*)d_in[2];
    const float* enc_bih  = (const float*)d_in[3];
    const float* enc_bhh  = (const float*)d_in[4];
    const float* dec_Wih  = (const float*)d_in[5];
    const float* dec_Whh  = (const float*)d_in[6];
    const float* dec_bih  = (const float*)d_in[7];
    const float* dec_bhh  = (const float*)d_in[8];
    const float* fc_W     = (const float*)d_in[9];
    const float* fc_b     = (const float*)d_in[10];
    float* out = (float*)d_out;

    const size_t wfrag = (size_t)HID * HID;
    _Float16* BwE = (_Float16*)d_ws;
    _Float16* BwD = BwE + wfrag;

    pack_wfrag<<<HID * HID / (256 * 8), 256, 0, stream>>>(enc_Whh, BwE);
    pack_wfrag<<<HID * HID / (256 * 8), 256, 0, stream>>>(dec_Whh, BwD);

    rnn_persist<<<NBLK, TPB, 0, stream>>>(
        x, BwE, BwD,
        enc_Wih, enc_bih, enc_bhh,
        dec_Wih, dec_bih, dec_bhh,
        fc_W, fc_b, out);
}